// Round 4
// baseline (163.441 us; speedup 1.0000x reference)
//
#include <hip/hip_runtime.h>
#include <stdint.h>
#include <stddef.h>

typedef _Float16 f16;
typedef f16 f16x4 __attribute__((ext_vector_type(4)));
typedef f16 f16x8 __attribute__((ext_vector_type(8)));
typedef float f32x4 __attribute__((ext_vector_type(4)));

#define DEV __device__ __forceinline__

constexpr int Bb = 4, Nn = 8192, Mm = 2048, C1 = 128, C2 = 256;
constexpr int K0 = 384, CO = 256;

// ---------------------------------------------------------------- 1) fused prep: kfT transpose (z<4) + weight repack (z==4)
__global__ __launch_bounds__(256) void prep_kernel(
    const float* __restrict__ kf, f16* __restrict__ kfT,
    const float* __restrict__ W0, const float* __restrict__ W1,
    f16* __restrict__ Af0, f16* __restrict__ Af1)
{
  const int t = threadIdx.x;
  if (blockIdx.z < 4) {
    // known_feats (B,C2,M) f32 -> kfT (B,M,C2) f16
    __shared__ f16 tile[64][72];
    const int m0 = blockIdx.x * 64, c0 = blockIdx.y * 64, b = blockIdx.z;
    const int lm = t & 63, row = t >> 6;
#pragma unroll
    for (int j = 0; j < 16; ++j) {
      int c = row + j * 4;
      tile[lm][c] = (f16)kf[(size_t)(b * C2 + c0 + c) * Mm + m0 + lm];
    }
    __syncthreads();
#pragma unroll
    for (int j = 0; j < 16; ++j) {
      int m = row + j * 4;
      kfT[(size_t)(b * Mm + m0 + m) * C2 + c0 + lm] = tile[m][lm];
    }
  } else {
    // weights f32 -> f16 in MFMA A-fragment order; 128 blocks x 256 thr x 3 iters = 98304 ids
    const int bid = blockIdx.y * 32 + blockIdx.x;
#pragma unroll
    for (int r = 0; r < 3; ++r) {
      int id = bid * 256 + t + r * 32768;
      int e = id & 7, lane = (id >> 3) & 63, mg = (id >> 9) & 15, ks = id >> 13;
      int m = mg * 16 + (lane & 15), k = ks * 32 + (lane >> 4) * 8 + e;
      if (id < CO * K0) Af0[id] = (f16)W0[m * K0 + k];
      if (id < CO * CO) Af1[id] = (f16)W1[m * CO + k];
    }
  }
}

// ---------------------------------------------------------------- 2) fully fused: three_nn + interp + concat + MLP0 + MLP1
// Phase A (knn): 4 waves x 512-candidate wave-uniform slices of the 32KB staged candidate set;
// per-pair math+selection is the verified 19-instr asm STEP (np-exact rounding chain:
// dot2 = fl(fl(fl(ux2*kx)+fl(uy2*ky))+fl(uz2*kz)), dd = fl(fl(uu-dot2)+kk); strict-less insert,
// increasing gm). Cross-wave merge is (d,i)-lexicographic => numpy-stable and
// partition-independent, so 4x512 gives bit-identical results to the verified 8x256.
// Per-query (idx,w) stay in LDS — no global round-trip, no device-wide barrier between
// knn and MLP; CU pipelines phase A of one block against phase B of another.
// Phase B: the verified mlp_fused body, reading idx/wts from LDS.
__global__ __launch_bounds__(256, 2) void fused_kernel(
    const float* __restrict__ unknown, const float* __restrict__ known,
    const f16* __restrict__ Af0, const f16* __restrict__ Af1,
    const f16* __restrict__ kfT, const float* __restrict__ uf,
    const float* __restrict__ bs0, const float* __restrict__ g0,
    const float* __restrict__ be0, const float* __restrict__ rm0, const float* __restrict__ rv0,
    const float* __restrict__ bs1, const float* __restrict__ g1,
    const float* __restrict__ be1, const float* __restrict__ rm1, const float* __restrict__ rv1,
    float* __restrict__ out)
{
  __shared__ __align__(16) char lds[54784];
  // [0,49152)      phase A: float4 sh[2048] (32KB) then merge arrays; phase B: B-tile
  // [49152,53248)  bn tables (4 x 1KB)
  // [53248,54016)  idxR[64][3] i32
  // [54016,54784)  wR[64][3] f32
  float4* sh    = (float4*)lds;
  float* mergeD = (float*)lds;                 // [4][64][3] f32 = 3 KB (after scan)
  int*   mergeI = (int*)(lds + 6144);          // [4][64][3] i32 = 3 KB
  float* bn0S = (float*)(lds + 49152);
  float* bn0H = (float*)(lds + 50176);
  float* bn1S = (float*)(lds + 51200);
  float* bn1H = (float*)(lds + 52224);
  int*   idxR = (int*)(lds + 53248);
  float* wR   = (float*)(lds + 54016);

  const int t = threadIdx.x;
  const int l = t & 63;
  const int w = __builtin_amdgcn_readfirstlane(t >> 6);   // wave id 0..3 (scalar)
  const int gid = blockIdx.x;
  const int b = gid >> 7, n0 = (gid & 127) * 64;

  // ---- stage all M candidates: 256 threads x 8 points, coalesced 12B/lane reads
#pragma unroll
  for (int j = 0; j < 8; ++j) {
    int m = t + j * 256;
    float kx = known[(b * Mm + m) * 3 + 0];
    float ky = known[(b * Mm + m) * 3 + 1];
    float kz = known[(b * Mm + m) * 3 + 2];
    float kk = __fadd_rn(__fadd_rn(__fmul_rn(kx, kx), __fmul_rn(ky, ky)), __fmul_rn(kz, kz));
    sh[m] = make_float4(kx, ky, kz, kk);
  }

  // bn tables (disjoint LDS region; overlaps staging latency)
  {
    float sc0 = g0[t] / sqrtf(rv0[t] + 1e-5f);
    bn0S[t] = sc0; bn0H[t] = (bs0[t] - rm0[t]) * sc0 + be0[t];
    float sc1 = g1[t] / sqrtf(rv1[t] + 1e-5f);
    bn1S[t] = sc1; bn1H[t] = (bs1[t] - rm1[t]) * sc1 + be1[t];
  }

  {
    const int q = n0 + l;
    float ux = unknown[(b * Nn + q) * 3 + 0];
    float uy = unknown[(b * Nn + q) * 3 + 1];
    float uz = unknown[(b * Nn + q) * 3 + 2];
    float uu = __fadd_rn(__fadd_rn(__fmul_rn(ux, ux), __fmul_rn(uy, uy)), __fmul_rn(uz, uz));
    float ux2 = ux + ux, uy2 = uy + uy, uz2 = uz + uz;   // exact (x2 = exponent bump)

    __syncthreads();

    const float4* wb = sh + (w << 9);    // wave-uniform 512-candidate slice
    float d1 = 1e30f, d2 = 1e30f, d3 = 1e30f;
    int   i1 = 0, i2 = 0, i3 = 0;
    int   gmv = w << 9;                  // running candidate index (VGPR, +1 per STEP)
    float tmp0, tmp1;
    uint64_t q1m, q2m;

    // 19-instr STEP: 7 np-exact math, 3 cmp, 3 med/min (spacing), 5 cndmask, 1 index inc.
#define STEP(kp) \
  asm( \
    "v_mul_f32 %[t], %[ux2], %[kx]\n\t" \
    "v_mul_f32 %[s], %[uy2], %[ky]\n\t" \
    "v_add_f32 %[t], %[t], %[s]\n\t" \
    "v_mul_f32 %[s], %[uz2], %[kz]\n\t" \
    "v_add_f32 %[t], %[t], %[s]\n\t" \
    "v_sub_f32 %[t], %[uu], %[t]\n\t" \
    "v_add_f32 %[t], %[t], %[kk]\n\t" \
    "v_cmp_lt_f32 %[q1], %[t], %[d1]\n\t" \
    "v_cmp_lt_f32 %[q2], %[t], %[d2]\n\t" \
    "v_cmp_lt_f32 vcc, %[t], %[d3]\n\t" \
    "v_med3_f32 %[d3], %[t], %[d2], %[d3]\n\t" \
    "v_med3_f32 %[d2], %[t], %[d1], %[d2]\n\t" \
    "v_min_f32 %[d1], %[t], %[d1]\n\t" \
    "v_cndmask_b32 %[s], %[gm], %[i2], %[q2]\n\t" \
    "v_cndmask_b32 %[i3], %[i3], %[s], vcc\n\t" \
    "v_cndmask_b32 %[s], %[gm], %[i1], %[q1]\n\t" \
    "v_cndmask_b32 %[i2], %[i2], %[s], %[q2]\n\t" \
    "v_cndmask_b32 %[i1], %[i1], %[gm], %[q1]\n\t" \
    "v_add_u32 %[gm], 1, %[gm]\n\t" \
    : [d1]"+v"(d1), [d2]"+v"(d2), [d3]"+v"(d3), \
      [i1]"+v"(i1), [i2]"+v"(i2), [i3]"+v"(i3), \
      [gm]"+v"(gmv), [t]"=&v"(tmp0), [s]"=&v"(tmp1), \
      [q1]"=&s"(q1m), [q2]"=&s"(q2m) \
    : [ux2]"v"(ux2), [uy2]"v"(uy2), [uz2]"v"(uz2), [uu]"v"(uu), \
      [kx]"v"((kp).x), [ky]"v"((kp).y), [kz]"v"((kp).z), [kk]"v"((kp).w) \
    : "vcc")

    float4 ca[4], cb[4];
#pragma unroll
    for (int j = 0; j < 4; ++j) ca[j] = wb[j];
#pragma unroll
    for (int j = 0; j < 4; ++j) cb[j] = wb[4 + j];

    for (int g = 0; g < 63; ++g) {                 // 8 candidates/iter; refill one group ahead
#pragma unroll
      for (int j = 0; j < 4; ++j) STEP(ca[j]);
#pragma unroll
      for (int j = 0; j < 4; ++j) ca[j] = wb[(g + 1) * 8 + j];
#pragma unroll
      for (int j = 0; j < 4; ++j) STEP(cb[j]);
#pragma unroll
      for (int j = 0; j < 4; ++j) cb[j] = wb[(g + 1) * 8 + 4 + j];
    }
#pragma unroll
    for (int j = 0; j < 4; ++j) STEP(ca[j]);
#pragma unroll
    for (int j = 0; j < 4; ++j) STEP(cb[j]);
#undef STEP

    // ---- per-wave partials -> LDS (reusing stage buffer), wave 0 merges (ties -> lower index)
    __syncthreads();                               // scan done, sh reusable
    mergeD[(w * 64 + l) * 3 + 0] = d1; mergeD[(w * 64 + l) * 3 + 1] = d2; mergeD[(w * 64 + l) * 3 + 2] = d3;
    mergeI[(w * 64 + l) * 3 + 0] = i1; mergeI[(w * 64 + l) * 3 + 1] = i2; mergeI[(w * 64 + l) * 3 + 2] = i3;
    __syncthreads();

    if (t < 64) {
      d1 = mergeD[t * 3 + 0]; d2 = mergeD[t * 3 + 1]; d3 = mergeD[t * 3 + 2];
      i1 = mergeI[t * 3 + 0]; i2 = mergeI[t * 3 + 1]; i3 = mergeI[t * 3 + 2];
#pragma unroll
      for (int ww = 1; ww < 4; ++ww) {
#pragma unroll
        for (int u = 0; u < 3; ++u) {
          float e = mergeD[(ww * 64 + t) * 3 + u];
          int   j = mergeI[(ww * 64 + t) * 3 + u];
          bool c3 = (e < d3) || (e == d3 && j < i3);
          bool c2 = (e < d2) || (e == d2 && j < i2);
          bool c1 = (e < d1) || (e == d1 && j < i1);
          d3 = c3 ? (c2 ? d2 : e) : d3;  i3 = c3 ? (c2 ? i2 : j) : i3;
          d2 = c2 ? (c1 ? d1 : e) : d2;  i2 = c2 ? (c1 ? i1 : j) : i2;
          d1 = c1 ? e : d1;              i1 = c1 ? j : i1;
        }
      }
      float t1 = sqrtf(fmaxf(d1, 0.f)), t2 = sqrtf(fmaxf(d2, 0.f)), t3 = sqrtf(fmaxf(d3, 0.f));
      float r1 = 1.f / (t1 + 1e-8f), r2 = 1.f / (t2 + 1e-8f), r3 = 1.f / (t3 + 1e-8f);
      float rs = __fadd_rn(__fadd_rn(r1, r2), r3);
      idxR[t * 3 + 0] = i1; idxR[t * 3 + 1] = i2; idxR[t * 3 + 2] = i3;
      wR[t * 3 + 0] = r1 / rs; wR[t * 3 + 1] = r2 / rs; wR[t * 3 + 2] = r3 / rs;
    }
  }
  __syncthreads();

  // ---------------- phase B: interp + concat + MLP0 + MLP1 (verified body, idx/wts from LDS)
  const int lm = l & 15, qq = l >> 4;

  {
    const int n = t >> 2, kg = t & 3;
    int i0 = idxR[n * 3 + 0], i1 = idxR[n * 3 + 1], i2 = idxR[n * 3 + 2];
    float w0 = wR[n * 3 + 0], w1 = wR[n * 3 + 1], w2 = wR[n * 3 + 2];
    f16 w0h = (f16)w0, w1h = (f16)w1, w2h = (f16)w2;
    f16x8 w0v = {w0h, w0h, w0h, w0h, w0h, w0h, w0h, w0h};
    f16x8 w1v = {w1h, w1h, w1h, w1h, w1h, w1h, w1h, w1h};
    f16x8 w2v = {w2h, w2h, w2h, w2h, w2h, w2h, w2h, w2h};
    const f16x8* r0 = (const f16x8*)(kfT + (size_t)(b * Mm + i0) * C2 + kg * 64);
    const f16x8* r1 = (const f16x8*)(kfT + (size_t)(b * Mm + i1) * C2 + kg * 64);
    const f16x8* r2 = (const f16x8*)(kfT + (size_t)(b * Mm + i2) * C2 + kg * 64);
    f16x8 v0[8], v1[8], v2[8];
#pragma unroll
    for (int j = 0; j < 8; ++j) { v0[j] = r0[j]; v1[j] = r1[j]; v2[j] = r2[j]; }
    __syncthreads();                               // idxR/wR read; sh region reusable for B-tile
#pragma unroll
    for (int j = 0; j < 8; ++j) {
      f16x8 o = v0[j] * w0v + v1[j] * w1v + v2[j] * w2v;
      int oct = kg * 8 + j;
      *(f16x8*)(lds + n * 768 + ((oct ^ (n & 7)) * 16)) = o;
    }
  }
  {
    const int n = t & 63, cb = (t >> 6) * 32;
    const float* src = uf + (size_t)(b * C1 + cb) * Nn + n0 + n;
#pragma unroll
    for (int jj = 0; jj < 4; ++jj) {
      f16x8 v;
#pragma unroll
      for (int e = 0; e < 8; ++e) v[e] = (f16)src[(size_t)(jj * 8 + e) * Nn];
      int oct = 32 + (cb >> 3) + jj;
      *(f16x8*)(lds + n * 768 + ((oct ^ (n & 7)) * 16)) = v;
    }
  }
  __syncthreads();

  f32x4 acc[4][4] = {};
  {
    f16x8 af[4];
#pragma unroll
    for (int i = 0; i < 4; ++i)
      af[i] = *(const f16x8*)(Af0 + ((size_t)(w * 4 + i) * 64 + l) * 8);
    for (int ks = 0; ks < 12; ++ks) {
      f16x8 afn[4];
      if (ks < 11) {
#pragma unroll
        for (int i = 0; i < 4; ++i)
          afn[i] = *(const f16x8*)(Af0 + ((size_t)((ks + 1) * 16 + w * 4 + i) * 64 + l) * 8);
      }
      f16x8 bf[4];
#pragma unroll
      for (int j = 0; j < 4; ++j) {
        int n = j * 16 + lm;
        bf[j] = *(const f16x8*)(lds + n * 768 + (((ks * 4 + qq) ^ (n & 7)) * 16));
      }
#pragma unroll
      for (int i = 0; i < 4; ++i)
#pragma unroll
        for (int j = 0; j < 4; ++j)
          acc[i][j] = __builtin_amdgcn_mfma_f32_16x16x32_f16(af[i], bf[j], acc[i][j], 0, 0, 0);
#pragma unroll
      for (int i = 0; i < 4; ++i) af[i] = afn[i];
    }
  }
  __syncthreads();

#pragma unroll
  for (int i = 0; i < 4; ++i) {
    const int mq = w * 64 + i * 16 + qq * 4;
    f32x4 s4 = *(const f32x4*)&bn0S[mq];
    f32x4 h4 = *(const f32x4*)&bn0H[mq];
#pragma unroll
    for (int j = 0; j < 4; ++j) {
      int n = j * 16 + lm;
      f16x4 v;
#pragma unroll
      for (int r = 0; r < 4; ++r) v[r] = (f16)fmaxf(fmaf(acc[i][j][r], s4[r], h4[r]), 0.f);
      *(f16x4*)(lds + n * 512 + (((mq >> 3) ^ (n & 7)) * 16) + (mq & 7) * 2) = v;
    }
  }
  __syncthreads();

#pragma unroll
  for (int i = 0; i < 4; ++i)
#pragma unroll
    for (int j = 0; j < 4; ++j) acc[i][j] = f32x4{0.f, 0.f, 0.f, 0.f};
  {
    f16x8 af[4];
#pragma unroll
    for (int i = 0; i < 4; ++i)
      af[i] = *(const f16x8*)(Af1 + ((size_t)(w * 4 + i) * 64 + l) * 8);
    for (int ks = 0; ks < 8; ++ks) {
      f16x8 afn[4];
      if (ks < 7) {
#pragma unroll
        for (int i = 0; i < 4; ++i)
          afn[i] = *(const f16x8*)(Af1 + ((size_t)((ks + 1) * 16 + w * 4 + i) * 64 + l) * 8);
      }
      f16x8 bf[4];
#pragma unroll
      for (int j = 0; j < 4; ++j) {
        int n = j * 16 + lm;
        bf[j] = *(const f16x8*)(lds + n * 512 + (((ks * 4 + qq) ^ (n & 7)) * 16));
      }
#pragma unroll
      for (int i = 0; i < 4; ++i)
#pragma unroll
        for (int j = 0; j < 4; ++j)
          acc[i][j] = __builtin_amdgcn_mfma_f32_16x16x32_f16(af[i], bf[j], acc[i][j], 0, 0, 0);
#pragma unroll
      for (int i = 0; i < 4; ++i) af[i] = afn[i];
    }
  }

#pragma unroll
  for (int i = 0; i < 4; ++i) {
    const int mq = w * 64 + i * 16 + qq * 4;
    f32x4 s4 = *(const f32x4*)&bn1S[mq];
    f32x4 h4 = *(const f32x4*)&bn1H[mq];
#pragma unroll
    for (int r = 0; r < 4; ++r) {
      const int m = mq + r;
#pragma unroll
      for (int j = 0; j < 4; ++j) {
        int n = j * 16 + lm;
        out[(size_t)(b * CO + m) * Nn + n0 + n] = fmaxf(fmaf(acc[i][j][r], s4[r], h4[r]), 0.f);
      }
    }
  }
}

// ---------------------------------------------------------------- launch
extern "C" void kernel_launch(void* const* d_in, const int* in_sizes, int n_in,
                              void* d_out, int out_size, void* d_ws, size_t ws_size,
                              hipStream_t stream)
{
  const float* unknown = (const float*)d_in[0];
  const float* known   = (const float*)d_in[1];
  const float* uf      = (const float*)d_in[2];
  const float* kf      = (const float*)d_in[3];
  const float* W0  = (const float*)d_in[4];
  const float* b0  = (const float*)d_in[5];
  const float* g0  = (const float*)d_in[6];
  const float* be0 = (const float*)d_in[7];
  const float* rm0 = (const float*)d_in[8];
  const float* rv0 = (const float*)d_in[9];
  const float* W1  = (const float*)d_in[10];
  const float* b1  = (const float*)d_in[11];
  const float* g1  = (const float*)d_in[12];
  const float* be1 = (const float*)d_in[13];
  const float* rm1 = (const float*)d_in[14];
  const float* rv1 = (const float*)d_in[15];

  char* ws = (char*)d_ws;
  f16* kfT = (f16*)(ws + 0);          // B*M*C2 f16 = 4 MB
  f16* Af0 = (f16*)(ws + 4194304);    // 256*384 f16 (fragment-order)
  f16* Af1 = (f16*)(ws + 4390912);    // 256*256 f16 (fragment-order)
  float* out = (float*)d_out;         // (B,256,N) f32

  prep_kernel <<<dim3(32, 4, 5), 256, 0, stream>>>(kf, kfT, W0, W1, Af0, Af1);
  fused_kernel<<<dim3(Bb * (Nn / 64)), 256, 0, stream>>>(
      unknown, known, Af0, Af1, kfT, uf,
      b0, g0, be0, rm0, rv0, b1, g1, be1, rm1, rv1, out);
}

// Round 5
// 152.784 us; speedup vs baseline: 1.0698x; 1.0698x over previous
//
#include <hip/hip_runtime.h>
#include <stdint.h>
#include <stddef.h>

typedef _Float16 f16;
typedef f16 f16x4 __attribute__((ext_vector_type(4)));
typedef f16 f16x8 __attribute__((ext_vector_type(8)));
typedef float f32x4 __attribute__((ext_vector_type(4)));

#define DEV __device__ __forceinline__

constexpr int Bb = 4, Nn = 8192, Mm = 2048, C1 = 128, C2 = 256;
constexpr int K0 = 384, CO = 256;

// ---------------------------------------------------------------- 1) fused prep: kfT transpose (z<4) + weight repack (z==4)
__global__ __launch_bounds__(256) void prep_kernel(
    const float* __restrict__ kf, f16* __restrict__ kfT,
    const float* __restrict__ W0, const float* __restrict__ W1,
    f16* __restrict__ Af0, f16* __restrict__ Af1)
{
  const int t = threadIdx.x;
  if (blockIdx.z < 4) {
    // known_feats (B,C2,M) f32 -> kfT (B,M,C2) f16
    __shared__ f16 tile[64][72];
    const int m0 = blockIdx.x * 64, c0 = blockIdx.y * 64, b = blockIdx.z;
    const int lm = t & 63, row = t >> 6;
#pragma unroll
    for (int j = 0; j < 16; ++j) {
      int c = row + j * 4;
      tile[lm][c] = (f16)kf[(size_t)(b * C2 + c0 + c) * Mm + m0 + lm];
    }
    __syncthreads();
#pragma unroll
    for (int j = 0; j < 16; ++j) {
      int m = row + j * 4;
      kfT[(size_t)(b * Mm + m0 + m) * C2 + c0 + lm] = tile[m][lm];
    }
  } else {
    // weights f32 -> f16 in MFMA A-fragment order; 128 blocks x 256 thr x 3 iters = 98304 ids
    const int bid = blockIdx.y * 32 + blockIdx.x;
#pragma unroll
    for (int r = 0; r < 3; ++r) {
      int id = bid * 256 + t + r * 32768;
      int e = id & 7, lane = (id >> 3) & 63, mg = (id >> 9) & 15, ks = id >> 13;
      int m = mg * 16 + (lane & 15), k = ks * 32 + (lane >> 4) * 8 + e;
      if (id < CO * K0) Af0[id] = (f16)W0[m * K0 + k];
      if (id < CO * CO) Af1[id] = (f16)W1[m * CO + k];
    }
  }
}

// ---------------------------------------------------------------- 2) fully fused: three_nn + interp + concat + MLP0 + MLP1
// 512 threads (8 waves), 2 blocks/CU -> 16 waves/CU (R3-knn's verified 85%-VALUBusy regime).
// Phase A: 8 waves x 256-candidate wave-uniform slices (exact R3 partition); per-pair
// math+selection is the verified 19-instr asm STEP (np-exact rounding chain:
// dot2 = fl(fl(fl(ux2*kx)+fl(uy2*ky))+fl(uz2*kz)), dd = fl(fl(uu-dot2)+kk); strict-less insert,
// increasing gm). Cross-wave merge is (d,i)-lexicographic => numpy-stable, partition-independent.
// Per-query (idx,w) stay in LDS. Phase B: 8-wave MLP — each wave owns 32 output rows
// (acc[2][4]); interp uses kg = wave-id so simultaneous lanes differ in n and the ^(n&7)
// swizzle spreads banks (kills the 1.18M conflicts measured in R4).
__global__ __launch_bounds__(512, 4) void fused_kernel(
    const float* __restrict__ unknown, const float* __restrict__ known,
    const f16* __restrict__ Af0, const f16* __restrict__ Af1,
    const f16* __restrict__ kfT, const float* __restrict__ uf,
    const float* __restrict__ bs0, const float* __restrict__ g0,
    const float* __restrict__ be0, const float* __restrict__ rm0, const float* __restrict__ rv0,
    const float* __restrict__ bs1, const float* __restrict__ g1,
    const float* __restrict__ be1, const float* __restrict__ rm1, const float* __restrict__ rv1,
    float* __restrict__ out)
{
  __shared__ __align__(16) char lds[54784];
  // [0,49152)      phase A: float4 sh[2048] (32KB) then merge arrays; phase B: B-tile
  // [49152,53248)  bn tables (4 x 1KB)
  // [53248,54016)  idxR[64][3] i32
  // [54016,54784)  wR[64][3] f32
  float4* sh    = (float4*)lds;
  float* mergeD = (float*)lds;                 // [8][64][3] f32 = 6 KB (after scan)
  int*   mergeI = (int*)(lds + 6144);          // [8][64][3] i32 = 6 KB
  float* bn0S = (float*)(lds + 49152);
  float* bn0H = (float*)(lds + 50176);
  float* bn1S = (float*)(lds + 51200);
  float* bn1H = (float*)(lds + 52224);
  int*   idxR = (int*)(lds + 53248);
  float* wR   = (float*)(lds + 54016);

  const int t = threadIdx.x;
  const int l = t & 63;
  const int w = __builtin_amdgcn_readfirstlane(t >> 6);   // wave id 0..7 (scalar)
  const int gid = blockIdx.x;
  const int b = gid >> 7, n0 = (gid & 127) * 64;

  // ---- stage all M candidates: 512 threads x 4 points, coalesced 12B/lane reads
#pragma unroll
  for (int j = 0; j < 4; ++j) {
    int m = t + j * 512;
    float kx = known[(b * Mm + m) * 3 + 0];
    float ky = known[(b * Mm + m) * 3 + 1];
    float kz = known[(b * Mm + m) * 3 + 2];
    float kk = __fadd_rn(__fadd_rn(__fmul_rn(kx, kx), __fmul_rn(ky, ky)), __fmul_rn(kz, kz));
    sh[m] = make_float4(kx, ky, kz, kk);
  }

  // bn tables (disjoint LDS region; overlaps staging latency)
  if (t < 256) {
    float sc0 = g0[t] / sqrtf(rv0[t] + 1e-5f);
    bn0S[t] = sc0; bn0H[t] = (bs0[t] - rm0[t]) * sc0 + be0[t];
    float sc1 = g1[t] / sqrtf(rv1[t] + 1e-5f);
    bn1S[t] = sc1; bn1H[t] = (bs1[t] - rm1[t]) * sc1 + be1[t];
  }

  {
    const int q = n0 + l;
    float ux = unknown[(b * Nn + q) * 3 + 0];
    float uy = unknown[(b * Nn + q) * 3 + 1];
    float uz = unknown[(b * Nn + q) * 3 + 2];
    float uu = __fadd_rn(__fadd_rn(__fmul_rn(ux, ux), __fmul_rn(uy, uy)), __fmul_rn(uz, uz));
    float ux2 = ux + ux, uy2 = uy + uy, uz2 = uz + uz;   // exact (x2 = exponent bump)

    __syncthreads();

    const float4* wb = sh + (w << 8);    // wave-uniform 256-candidate slice
    float d1 = 1e30f, d2 = 1e30f, d3 = 1e30f;
    int   i1 = 0, i2 = 0, i3 = 0;
    int   gmv = w << 8;                  // running candidate index (VGPR, +1 per STEP)
    float tmp0, tmp1;
    uint64_t q1m, q2m;

    // 19-instr STEP: 7 np-exact math, 3 cmp, 3 med/min (spacing), 5 cndmask, 1 index inc.
#define STEP(kp) \
  asm( \
    "v_mul_f32 %[t], %[ux2], %[kx]\n\t" \
    "v_mul_f32 %[s], %[uy2], %[ky]\n\t" \
    "v_add_f32 %[t], %[t], %[s]\n\t" \
    "v_mul_f32 %[s], %[uz2], %[kz]\n\t" \
    "v_add_f32 %[t], %[t], %[s]\n\t" \
    "v_sub_f32 %[t], %[uu], %[t]\n\t" \
    "v_add_f32 %[t], %[t], %[kk]\n\t" \
    "v_cmp_lt_f32 %[q1], %[t], %[d1]\n\t" \
    "v_cmp_lt_f32 %[q2], %[t], %[d2]\n\t" \
    "v_cmp_lt_f32 vcc, %[t], %[d3]\n\t" \
    "v_med3_f32 %[d3], %[t], %[d2], %[d3]\n\t" \
    "v_med3_f32 %[d2], %[t], %[d1], %[d2]\n\t" \
    "v_min_f32 %[d1], %[t], %[d1]\n\t" \
    "v_cndmask_b32 %[s], %[gm], %[i2], %[q2]\n\t" \
    "v_cndmask_b32 %[i3], %[i3], %[s], vcc\n\t" \
    "v_cndmask_b32 %[s], %[gm], %[i1], %[q1]\n\t" \
    "v_cndmask_b32 %[i2], %[i2], %[s], %[q2]\n\t" \
    "v_cndmask_b32 %[i1], %[i1], %[gm], %[q1]\n\t" \
    "v_add_u32 %[gm], 1, %[gm]\n\t" \
    : [d1]"+v"(d1), [d2]"+v"(d2), [d3]"+v"(d3), \
      [i1]"+v"(i1), [i2]"+v"(i2), [i3]"+v"(i3), \
      [gm]"+v"(gmv), [t]"=&v"(tmp0), [s]"=&v"(tmp1), \
      [q1]"=&s"(q1m), [q2]"=&s"(q2m) \
    : [ux2]"v"(ux2), [uy2]"v"(uy2), [uz2]"v"(uz2), [uu]"v"(uu), \
      [kx]"v"((kp).x), [ky]"v"((kp).y), [kz]"v"((kp).z), [kk]"v"((kp).w) \
    : "vcc")

    float4 ca[4], cb[4];
#pragma unroll
    for (int j = 0; j < 4; ++j) ca[j] = wb[j];
#pragma unroll
    for (int j = 0; j < 4; ++j) cb[j] = wb[4 + j];

    for (int g = 0; g < 31; ++g) {                 // 8 candidates/iter; refill one group ahead
#pragma unroll
      for (int j = 0; j < 4; ++j) STEP(ca[j]);
#pragma unroll
      for (int j = 0; j < 4; ++j) ca[j] = wb[(g + 1) * 8 + j];
#pragma unroll
      for (int j = 0; j < 4; ++j) STEP(cb[j]);
#pragma unroll
      for (int j = 0; j < 4; ++j) cb[j] = wb[(g + 1) * 8 + 4 + j];
    }
#pragma unroll
    for (int j = 0; j < 4; ++j) STEP(ca[j]);
#pragma unroll
    for (int j = 0; j < 4; ++j) STEP(cb[j]);
#undef STEP

    // ---- per-wave partials -> LDS (reusing stage buffer), wave 0 merges (ties -> lower index)
    __syncthreads();                               // scan done, sh reusable
    mergeD[(w * 64 + l) * 3 + 0] = d1; mergeD[(w * 64 + l) * 3 + 1] = d2; mergeD[(w * 64 + l) * 3 + 2] = d3;
    mergeI[(w * 64 + l) * 3 + 0] = i1; mergeI[(w * 64 + l) * 3 + 1] = i2; mergeI[(w * 64 + l) * 3 + 2] = i3;
    __syncthreads();

    if (t < 64) {
      d1 = mergeD[t * 3 + 0]; d2 = mergeD[t * 3 + 1]; d3 = mergeD[t * 3 + 2];
      i1 = mergeI[t * 3 + 0]; i2 = mergeI[t * 3 + 1]; i3 = mergeI[t * 3 + 2];
#pragma unroll
      for (int ww = 1; ww < 8; ++ww) {
#pragma unroll
        for (int u = 0; u < 3; ++u) {
          float e = mergeD[(ww * 64 + t) * 3 + u];
          int   j = mergeI[(ww * 64 + t) * 3 + u];
          bool c3 = (e < d3) || (e == d3 && j < i3);
          bool c2 = (e < d2) || (e == d2 && j < i2);
          bool c1 = (e < d1) || (e == d1 && j < i1);
          d3 = c3 ? (c2 ? d2 : e) : d3;  i3 = c3 ? (c2 ? i2 : j) : i3;
          d2 = c2 ? (c1 ? d1 : e) : d2;  i2 = c2 ? (c1 ? i1 : j) : i2;
          d1 = c1 ? e : d1;              i1 = c1 ? j : i1;
        }
      }
      float t1 = sqrtf(fmaxf(d1, 0.f)), t2 = sqrtf(fmaxf(d2, 0.f)), t3 = sqrtf(fmaxf(d3, 0.f));
      float r1 = 1.f / (t1 + 1e-8f), r2 = 1.f / (t2 + 1e-8f), r3 = 1.f / (t3 + 1e-8f);
      float rs = __fadd_rn(__fadd_rn(r1, r2), r3);
      idxR[t * 3 + 0] = i1; idxR[t * 3 + 1] = i2; idxR[t * 3 + 2] = i3;
      wR[t * 3 + 0] = r1 / rs; wR[t * 3 + 1] = r2 / rs; wR[t * 3 + 2] = r3 / rs;
    }
  }
  __syncthreads();

  // ---------------- phase B: interp + concat + MLP0 + MLP1 (8-wave layout, idx/wts from LDS)
  const int lm = l & 15, qq = l >> 4;

  {
    // kg = wave id (wave-uniform), n = lane -> simultaneous lanes differ in n; ^(n&7)
    // swizzle spreads banks (conflict-free 2-way quarters).
    const int n = l, kg = w;
    int i0 = idxR[n * 3 + 0], i1 = idxR[n * 3 + 1], i2 = idxR[n * 3 + 2];
    float w0 = wR[n * 3 + 0], w1 = wR[n * 3 + 1], w2 = wR[n * 3 + 2];
    f16 w0h = (f16)w0, w1h = (f16)w1, w2h = (f16)w2;
    f16x8 w0v = {w0h, w0h, w0h, w0h, w0h, w0h, w0h, w0h};
    f16x8 w1v = {w1h, w1h, w1h, w1h, w1h, w1h, w1h, w1h};
    f16x8 w2v = {w2h, w2h, w2h, w2h, w2h, w2h, w2h, w2h};
    const f16x8* r0 = (const f16x8*)(kfT + (size_t)(b * Mm + i0) * C2 + kg * 32);
    const f16x8* r1 = (const f16x8*)(kfT + (size_t)(b * Mm + i1) * C2 + kg * 32);
    const f16x8* r2 = (const f16x8*)(kfT + (size_t)(b * Mm + i2) * C2 + kg * 32);
#pragma unroll
    for (int j = 0; j < 4; ++j) {
      f16x8 o = r0[j] * w0v + r1[j] * w1v + r2[j] * w2v;
      int oct = kg * 4 + j;
      *(f16x8*)(lds + n * 768 + ((oct ^ (n & 7)) * 16)) = o;
    }
  }
  {
    const int n = l, cb = w * 16;
    const float* src = uf + (size_t)(b * C1 + cb) * Nn + n0 + n;
#pragma unroll
    for (int jj = 0; jj < 2; ++jj) {
      f16x8 v;
#pragma unroll
      for (int e = 0; e < 8; ++e) v[e] = (f16)src[(size_t)(jj * 8 + e) * Nn];
      int oct = 32 + w * 2 + jj;
      *(f16x8*)(lds + n * 768 + ((oct ^ (n & 7)) * 16)) = v;
    }
  }
  __syncthreads();

  f32x4 acc[2][4] = {};
  {
    f16x8 af[2];
#pragma unroll
    for (int i = 0; i < 2; ++i)
      af[i] = *(const f16x8*)(Af0 + ((size_t)(w * 2 + i) * 64 + l) * 8);
    for (int ks = 0; ks < 12; ++ks) {
      f16x8 afn[2];
      if (ks < 11) {
#pragma unroll
        for (int i = 0; i < 2; ++i)
          afn[i] = *(const f16x8*)(Af0 + ((size_t)((ks + 1) * 16 + w * 2 + i) * 64 + l) * 8);
      }
      f16x8 bf[4];
#pragma unroll
      for (int j = 0; j < 4; ++j) {
        int n = j * 16 + lm;
        bf[j] = *(const f16x8*)(lds + n * 768 + (((ks * 4 + qq) ^ (n & 7)) * 16));
      }
#pragma unroll
      for (int i = 0; i < 2; ++i)
#pragma unroll
        for (int j = 0; j < 4; ++j)
          acc[i][j] = __builtin_amdgcn_mfma_f32_16x16x32_f16(af[i], bf[j], acc[i][j], 0, 0, 0);
#pragma unroll
      for (int i = 0; i < 2; ++i) af[i] = afn[i];
    }
  }
  __syncthreads();

#pragma unroll
  for (int i = 0; i < 2; ++i) {
    const int mq = w * 32 + i * 16 + qq * 4;
    f32x4 s4 = *(const f32x4*)&bn0S[mq];
    f32x4 h4 = *(const f32x4*)&bn0H[mq];
#pragma unroll
    for (int j = 0; j < 4; ++j) {
      int n = j * 16 + lm;
      f16x4 v;
#pragma unroll
      for (int r = 0; r < 4; ++r) v[r] = (f16)fmaxf(fmaf(acc[i][j][r], s4[r], h4[r]), 0.f);
      *(f16x4*)(lds + n * 512 + (((mq >> 3) ^ (n & 7)) * 16) + (mq & 7) * 2) = v;
    }
  }
  __syncthreads();

#pragma unroll
  for (int i = 0; i < 2; ++i)
#pragma unroll
    for (int j = 0; j < 4; ++j) acc[i][j] = f32x4{0.f, 0.f, 0.f, 0.f};
  {
    f16x8 af[2];
#pragma unroll
    for (int i = 0; i < 2; ++i)
      af[i] = *(const f16x8*)(Af1 + ((size_t)(w * 2 + i) * 64 + l) * 8);
    for (int ks = 0; ks < 8; ++ks) {
      f16x8 afn[2];
      if (ks < 7) {
#pragma unroll
        for (int i = 0; i < 2; ++i)
          afn[i] = *(const f16x8*)(Af1 + ((size_t)((ks + 1) * 16 + w * 2 + i) * 64 + l) * 8);
      }
      f16x8 bf[4];
#pragma unroll
      for (int j = 0; j < 4; ++j) {
        int n = j * 16 + lm;
        bf[j] = *(const f16x8*)(lds + n * 512 + (((ks * 4 + qq) ^ (n & 7)) * 16));
      }
#pragma unroll
      for (int i = 0; i < 2; ++i)
#pragma unroll
        for (int j = 0; j < 4; ++j)
          acc[i][j] = __builtin_amdgcn_mfma_f32_16x16x32_f16(af[i], bf[j], acc[i][j], 0, 0, 0);
#pragma unroll
      for (int i = 0; i < 2; ++i) af[i] = afn[i];
    }
  }

#pragma unroll
  for (int i = 0; i < 2; ++i) {
    const int mq = w * 32 + i * 16 + qq * 4;
    f32x4 s4 = *(const f32x4*)&bn1S[mq];
    f32x4 h4 = *(const f32x4*)&bn1H[mq];
#pragma unroll
    for (int r = 0; r < 4; ++r) {
      const int m = mq + r;
#pragma unroll
      for (int j = 0; j < 4; ++j) {
        int n = j * 16 + lm;
        out[(size_t)(b * CO + m) * Nn + n0 + n] = fmaxf(fmaf(acc[i][j][r], s4[r], h4[r]), 0.f);
      }
    }
  }
}

// ---------------------------------------------------------------- launch
extern "C" void kernel_launch(void* const* d_in, const int* in_sizes, int n_in,
                              void* d_out, int out_size, void* d_ws, size_t ws_size,
                              hipStream_t stream)
{
  const float* unknown = (const float*)d_in[0];
  const float* known   = (const float*)d_in[1];
  const float* uf      = (const float*)d_in[2];
  const float* kf      = (const float*)d_in[3];
  const float* W0  = (const float*)d_in[4];
  const float* b0  = (const float*)d_in[5];
  const float* g0  = (const float*)d_in[6];
  const float* be0 = (const float*)d_in[7];
  const float* rm0 = (const float*)d_in[8];
  const float* rv0 = (const float*)d_in[9];
  const float* W1  = (const float*)d_in[10];
  const float* b1  = (const float*)d_in[11];
  const float* g1  = (const float*)d_in[12];
  const float* be1 = (const float*)d_in[13];
  const float* rm1 = (const float*)d_in[14];
  const float* rv1 = (const float*)d_in[15];

  char* ws = (char*)d_ws;
  f16* kfT = (f16*)(ws + 0);          // B*M*C2 f16 = 4 MB
  f16* Af0 = (f16*)(ws + 4194304);    // 256*384 f16 (fragment-order)
  f16* Af1 = (f16*)(ws + 4390912);    // 256*256 f16 (fragment-order)
  float* out = (float*)d_out;         // (B,256,N) f32

  prep_kernel <<<dim3(32, 4, 5), 256, 0, stream>>>(kf, kfT, W0, W1, Af0, Af1);
  fused_kernel<<<dim3(Bb * (Nn / 64)), 512, 0, stream>>>(
      unknown, known, Af0, Af1, kfT, uf,
      b0, g0, be0, rm0, rv0, b1, g1, be1, rm1, rv1, out);
}

// Round 6
// 147.683 us; speedup vs baseline: 1.1067x; 1.0345x over previous
//
#include <hip/hip_runtime.h>
#include <stdint.h>
#include <stddef.h>

typedef _Float16 f16;
typedef f16 f16x4 __attribute__((ext_vector_type(4)));
typedef f16 f16x8 __attribute__((ext_vector_type(8)));
typedef float f32x4 __attribute__((ext_vector_type(4)));

#define DEV __device__ __forceinline__

constexpr int Bb = 4, Nn = 8192, Mm = 2048, C1 = 128, C2 = 256;
constexpr int K0 = 384, CO = 256;

// ---------------------------------------------------------------- 1) fused prep: kfT transpose (z<4) + weight repack (z==4)
__global__ __launch_bounds__(256) void prep_kernel(
    const float* __restrict__ kf, f16* __restrict__ kfT,
    const float* __restrict__ W0, const float* __restrict__ W1,
    f16* __restrict__ Af0, f16* __restrict__ Af1)
{
  const int t = threadIdx.x;
  if (blockIdx.z < 4) {
    // known_feats (B,C2,M) f32 -> kfT (B,M,C2) f16
    __shared__ f16 tile[64][72];
    const int m0 = blockIdx.x * 64, c0 = blockIdx.y * 64, b = blockIdx.z;
    const int lm = t & 63, row = t >> 6;
#pragma unroll
    for (int j = 0; j < 16; ++j) {
      int c = row + j * 4;
      tile[lm][c] = (f16)kf[(size_t)(b * C2 + c0 + c) * Mm + m0 + lm];
    }
    __syncthreads();
#pragma unroll
    for (int j = 0; j < 16; ++j) {
      int m = row + j * 4;
      kfT[(size_t)(b * Mm + m0 + m) * C2 + c0 + lm] = tile[m][lm];
    }
  } else {
    // weights f32 -> f16 in MFMA A-fragment order; 128 blocks x 256 thr x 3 iters = 98304 ids
    const int bid = blockIdx.y * 32 + blockIdx.x;
#pragma unroll
    for (int r = 0; r < 3; ++r) {
      int id = bid * 256 + t + r * 32768;
      int e = id & 7, lane = (id >> 3) & 63, mg = (id >> 9) & 15, ks = id >> 13;
      int m = mg * 16 + (lane & 15), k = ks * 32 + (lane >> 4) * 8 + e;
      if (id < CO * K0) Af0[id] = (f16)W0[m * K0 + k];
      if (id < CO * CO) Af1[id] = (f16)W1[m * CO + k];
    }
  }
}

// ---------------------------------------------------------------- 2) fully fused: three_nn + interp + concat + MLP0 + MLP1
// 32 queries/block, 1024 blocks, 512 thr (8 waves), LDS 37.6KB -> 4 blocks/CU (32 waves/CU,
// 2x R5 residency; 4 co-resident blocks overlap phase-A VALU with phase-B MFMA/LDS).
// Phase A: lane owns query (l&31); lane-half (l>>5) scans half of wave w's 256-cand slice
// (128 STEPs/lane — same total pairs). Per-pair math+selection is the verified 19-instr asm
// STEP (np-exact chain: dot2 = fl(fl(fl(ux2*kx)+fl(uy2*ky))+fl(uz2*kz)), dd = fl(fl(uu-dot2)+kk);
// strict-less insert, increasing gm). 16 partials/query merged with the (d,i)-lexicographic
// rule => numpy-stable, partition-independent (verified across 8x256 and 4x512 repartitions).
// Phase B: N=32 MLP tile — acc[2][2]/wave, j in {0,1}; same swizzles/epilogues as R5.
__global__ __launch_bounds__(512, 8) void fused_kernel(
    const float* __restrict__ unknown, const float* __restrict__ known,
    const f16* __restrict__ Af0, const f16* __restrict__ Af1,
    const f16* __restrict__ kfT, const float* __restrict__ uf,
    const float* __restrict__ bs0, const float* __restrict__ g0,
    const float* __restrict__ be0, const float* __restrict__ rm0, const float* __restrict__ rv0,
    const float* __restrict__ bs1, const float* __restrict__ g1,
    const float* __restrict__ be1, const float* __restrict__ rm1, const float* __restrict__ rv1,
    float* __restrict__ out)
{
  __shared__ __align__(16) char lds[37632];
  // [0,32768)      phase A: float4 sh[2048] (32KB) then merge arrays; phase B: B-tile (24.5KB)
  //                and MLP1 tile (16KB)
  // [32768,36864)  bn tables (4 x 1KB)
  // [36864,37248)  idxR[32][3] i32
  // [37248,37632)  wR[32][3] f32
  float4* sh    = (float4*)lds;
  float* mergeD = (float*)lds;                 // [16][32][3] f32 = 6 KB (after scan)
  int*   mergeI = (int*)(lds + 6144);          // [16][32][3] i32 = 6 KB
  float* bn0S = (float*)(lds + 32768);
  float* bn0H = (float*)(lds + 33792);
  float* bn1S = (float*)(lds + 34816);
  float* bn1H = (float*)(lds + 35840);
  int*   idxR = (int*)(lds + 36864);
  float* wR   = (float*)(lds + 37248);

  const int t = threadIdx.x;
  const int l = t & 63;
  const int w = __builtin_amdgcn_readfirstlane(t >> 6);   // wave id 0..7 (scalar)
  const int gid = blockIdx.x;
  const int b = gid >> 8, n0 = (gid & 255) * 32;          // 256 blocks per batch

  // ---- stage all M candidates: 512 threads x 4 points, coalesced 12B/lane reads
#pragma unroll
  for (int j = 0; j < 4; ++j) {
    int m = t + j * 512;
    float kx = known[(b * Mm + m) * 3 + 0];
    float ky = known[(b * Mm + m) * 3 + 1];
    float kz = known[(b * Mm + m) * 3 + 2];
    float kk = __fadd_rn(__fadd_rn(__fmul_rn(kx, kx), __fmul_rn(ky, ky)), __fmul_rn(kz, kz));
    sh[m] = make_float4(kx, ky, kz, kk);
  }

  // bn tables (disjoint LDS region; overlaps staging latency)
  if (t < 256) {
    float sc0 = g0[t] / sqrtf(rv0[t] + 1e-5f);
    bn0S[t] = sc0; bn0H[t] = (bs0[t] - rm0[t]) * sc0 + be0[t];
    float sc1 = g1[t] / sqrtf(rv1[t] + 1e-5f);
    bn1S[t] = sc1; bn1H[t] = (bs1[t] - rm1[t]) * sc1 + be1[t];
  }

  {
    const int q = n0 + (l & 31);
    const int h = l >> 5;                       // lane-half: which 128-cand sub-slice
    float ux = unknown[(b * Nn + q) * 3 + 0];
    float uy = unknown[(b * Nn + q) * 3 + 1];
    float uz = unknown[(b * Nn + q) * 3 + 2];
    float uu = __fadd_rn(__fadd_rn(__fmul_rn(ux, ux), __fmul_rn(uy, uy)), __fmul_rn(uz, uz));
    float ux2 = ux + ux, uy2 = uy + uy, uz2 = uz + uz;   // exact (x2 = exponent bump)

    __syncthreads();

    const float4* wb = sh + (w << 8) + (h << 7);  // per-lane-half 128-cand slice
    float d1 = 1e30f, d2 = 1e30f, d3 = 1e30f;
    int   i1 = 0, i2 = 0, i3 = 0;
    int   gmv = (w << 8) + (h << 7);              // running candidate index (VGPR, +1 per STEP)
    float tmp0, tmp1;
    uint64_t q1m, q2m;

    // 19-instr STEP: 7 np-exact math, 3 cmp, 3 med/min (spacing), 5 cndmask, 1 index inc.
#define STEP(kp) \
  asm( \
    "v_mul_f32 %[t], %[ux2], %[kx]\n\t" \
    "v_mul_f32 %[s], %[uy2], %[ky]\n\t" \
    "v_add_f32 %[t], %[t], %[s]\n\t" \
    "v_mul_f32 %[s], %[uz2], %[kz]\n\t" \
    "v_add_f32 %[t], %[t], %[s]\n\t" \
    "v_sub_f32 %[t], %[uu], %[t]\n\t" \
    "v_add_f32 %[t], %[t], %[kk]\n\t" \
    "v_cmp_lt_f32 %[q1], %[t], %[d1]\n\t" \
    "v_cmp_lt_f32 %[q2], %[t], %[d2]\n\t" \
    "v_cmp_lt_f32 vcc, %[t], %[d3]\n\t" \
    "v_med3_f32 %[d3], %[t], %[d2], %[d3]\n\t" \
    "v_med3_f32 %[d2], %[t], %[d1], %[d2]\n\t" \
    "v_min_f32 %[d1], %[t], %[d1]\n\t" \
    "v_cndmask_b32 %[s], %[gm], %[i2], %[q2]\n\t" \
    "v_cndmask_b32 %[i3], %[i3], %[s], vcc\n\t" \
    "v_cndmask_b32 %[s], %[gm], %[i1], %[q1]\n\t" \
    "v_cndmask_b32 %[i2], %[i2], %[s], %[q2]\n\t" \
    "v_cndmask_b32 %[i1], %[i1], %[gm], %[q1]\n\t" \
    "v_add_u32 %[gm], 1, %[gm]\n\t" \
    : [d1]"+v"(d1), [d2]"+v"(d2), [d3]"+v"(d3), \
      [i1]"+v"(i1), [i2]"+v"(i2), [i3]"+v"(i3), \
      [gm]"+v"(gmv), [t]"=&v"(tmp0), [s]"=&v"(tmp1), \
      [q1]"=&s"(q1m), [q2]"=&s"(q2m) \
    : [ux2]"v"(ux2), [uy2]"v"(uy2), [uz2]"v"(uz2), [uu]"v"(uu), \
      [kx]"v"((kp).x), [ky]"v"((kp).y), [kz]"v"((kp).z), [kk]"v"((kp).w) \
    : "vcc")

    float4 ca[4], cb[4];
#pragma unroll
    for (int j = 0; j < 4; ++j) ca[j] = wb[j];
#pragma unroll
    for (int j = 0; j < 4; ++j) cb[j] = wb[4 + j];

    for (int g = 0; g < 15; ++g) {               // 8 candidates/iter; refill one group ahead
#pragma unroll
      for (int j = 0; j < 4; ++j) STEP(ca[j]);
#pragma unroll
      for (int j = 0; j < 4; ++j) ca[j] = wb[(g + 1) * 8 + j];
#pragma unroll
      for (int j = 0; j < 4; ++j) STEP(cb[j]);
#pragma unroll
      for (int j = 0; j < 4; ++j) cb[j] = wb[(g + 1) * 8 + 4 + j];
    }
#pragma unroll
    for (int j = 0; j < 4; ++j) STEP(ca[j]);
#pragma unroll
    for (int j = 0; j < 4; ++j) STEP(cb[j]);
#undef STEP

    // ---- 16 partials per query -> LDS (reusing stage buffer); t<32 merges (ties -> lower idx)
    __syncthreads();                             // scan done, sh reusable
    // flat slot-query index (w*64+l) == ((w*2+h)*32 + (l&31))
    mergeD[(w * 64 + l) * 3 + 0] = d1; mergeD[(w * 64 + l) * 3 + 1] = d2; mergeD[(w * 64 + l) * 3 + 2] = d3;
    mergeI[(w * 64 + l) * 3 + 0] = i1; mergeI[(w * 64 + l) * 3 + 1] = i2; mergeI[(w * 64 + l) * 3 + 2] = i3;
    __syncthreads();

    if (t < 32) {
      d1 = mergeD[t * 3 + 0]; d2 = mergeD[t * 3 + 1]; d3 = mergeD[t * 3 + 2];
      i1 = mergeI[t * 3 + 0]; i2 = mergeI[t * 3 + 1]; i3 = mergeI[t * 3 + 2];
#pragma unroll
      for (int ww = 1; ww < 16; ++ww) {
#pragma unroll
        for (int u = 0; u < 3; ++u) {
          float e = mergeD[(ww * 32 + t) * 3 + u];
          int   j = mergeI[(ww * 32 + t) * 3 + u];
          bool c3 = (e < d3) || (e == d3 && j < i3);
          bool c2 = (e < d2) || (e == d2 && j < i2);
          bool c1 = (e < d1) || (e == d1 && j < i1);
          d3 = c3 ? (c2 ? d2 : e) : d3;  i3 = c3 ? (c2 ? i2 : j) : i3;
          d2 = c2 ? (c1 ? d1 : e) : d2;  i2 = c2 ? (c1 ? i1 : j) : i2;
          d1 = c1 ? e : d1;              i1 = c1 ? j : i1;
        }
      }
      float t1 = sqrtf(fmaxf(d1, 0.f)), t2 = sqrtf(fmaxf(d2, 0.f)), t3 = sqrtf(fmaxf(d3, 0.f));
      float r1 = 1.f / (t1 + 1e-8f), r2 = 1.f / (t2 + 1e-8f), r3 = 1.f / (t3 + 1e-8f);
      float rs = __fadd_rn(__fadd_rn(r1, r2), r3);
      idxR[t * 3 + 0] = i1; idxR[t * 3 + 1] = i2; idxR[t * 3 + 2] = i3;
      wR[t * 3 + 0] = r1 / rs; wR[t * 3 + 1] = r2 / rs; wR[t * 3 + 2] = r3 / rs;
    }
  }
  __syncthreads();

  // ---------------- phase B: interp + concat + MLP0 + MLP1 (N=32 tile, idx/wts from LDS)
  const int lm = l & 15, qq = l >> 4;

  {
    // lane: query q = l&31, half h = l>>5; produces octs {4w+2h, 4w+2h+1} for its query.
    const int q = l & 31, h = l >> 5;
    const int o0 = w * 4 + h * 2;
    int i0 = idxR[q * 3 + 0], i1 = idxR[q * 3 + 1], i2 = idxR[q * 3 + 2];
    float w0 = wR[q * 3 + 0], w1 = wR[q * 3 + 1], w2 = wR[q * 3 + 2];
    f16 w0h = (f16)w0, w1h = (f16)w1, w2h = (f16)w2;
    f16x8 w0v = {w0h, w0h, w0h, w0h, w0h, w0h, w0h, w0h};
    f16x8 w1v = {w1h, w1h, w1h, w1h, w1h, w1h, w1h, w1h};
    f16x8 w2v = {w2h, w2h, w2h, w2h, w2h, w2h, w2h, w2h};
    const f16x8* r0 = (const f16x8*)(kfT + (size_t)(b * Mm + i0) * C2 + o0 * 8);
    const f16x8* r1 = (const f16x8*)(kfT + (size_t)(b * Mm + i1) * C2 + o0 * 8);
    const f16x8* r2 = (const f16x8*)(kfT + (size_t)(b * Mm + i2) * C2 + o0 * 8);
    f16x8 v0[2], v1[2], v2[2];
#pragma unroll
    for (int j = 0; j < 2; ++j) { v0[j] = r0[j]; v1[j] = r1[j]; v2[j] = r2[j]; }
    __syncthreads();                             // idxR/wR read; merge region reusable for B-tile
#pragma unroll
    for (int j = 0; j < 2; ++j) {
      f16x8 o = v0[j] * w0v + v1[j] * w1v + v2[j] * w2v;
      int oct = o0 + j;
      *(f16x8*)(lds + q * 768 + ((oct ^ (q & 7)) * 16)) = o;
    }
  }
  {
    const int q = l & 31, h = l >> 5;
    const int cu = (w * 2 + h) * 8;              // uf channel base; oct 32 + w*2 + h
    const float* src = uf + (size_t)(b * C1 + cu) * Nn + n0 + q;
    f16x8 v;
#pragma unroll
    for (int e = 0; e < 8; ++e) v[e] = (f16)src[(size_t)e * Nn];
    int oct = 32 + w * 2 + h;
    *(f16x8*)(lds + q * 768 + ((oct ^ (q & 7)) * 16)) = v;
  }
  __syncthreads();

  f32x4 acc[2][2] = {};
  {
    f16x8 af[2];
#pragma unroll
    for (int i = 0; i < 2; ++i)
      af[i] = *(const f16x8*)(Af0 + ((size_t)(w * 2 + i) * 64 + l) * 8);
    for (int ks = 0; ks < 12; ++ks) {
      f16x8 afn[2];
      if (ks < 11) {
#pragma unroll
        for (int i = 0; i < 2; ++i)
          afn[i] = *(const f16x8*)(Af0 + ((size_t)((ks + 1) * 16 + w * 2 + i) * 64 + l) * 8);
      }
      f16x8 bf[2];
#pragma unroll
      for (int j = 0; j < 2; ++j) {
        int n = j * 16 + lm;
        bf[j] = *(const f16x8*)(lds + n * 768 + (((ks * 4 + qq) ^ (n & 7)) * 16));
      }
#pragma unroll
      for (int i = 0; i < 2; ++i)
#pragma unroll
        for (int j = 0; j < 2; ++j)
          acc[i][j] = __builtin_amdgcn_mfma_f32_16x16x32_f16(af[i], bf[j], acc[i][j], 0, 0, 0);
#pragma unroll
      for (int i = 0; i < 2; ++i) af[i] = afn[i];
    }
  }
  __syncthreads();

#pragma unroll
  for (int i = 0; i < 2; ++i) {
    const int mq = w * 32 + i * 16 + qq * 4;
    f32x4 s4 = *(const f32x4*)&bn0S[mq];
    f32x4 h4 = *(const f32x4*)&bn0H[mq];
#pragma unroll
    for (int j = 0; j < 2; ++j) {
      int n = j * 16 + lm;
      f16x4 v;
#pragma unroll
      for (int r = 0; r < 4; ++r) v[r] = (f16)fmaxf(fmaf(acc[i][j][r], s4[r], h4[r]), 0.f);
      *(f16x4*)(lds + n * 512 + (((mq >> 3) ^ (n & 7)) * 16) + (mq & 7) * 2) = v;
    }
  }
  __syncthreads();

#pragma unroll
  for (int i = 0; i < 2; ++i)
#pragma unroll
    for (int j = 0; j < 2; ++j) acc[i][j] = f32x4{0.f, 0.f, 0.f, 0.f};
  {
    f16x8 af[2];
#pragma unroll
    for (int i = 0; i < 2; ++i)
      af[i] = *(const f16x8*)(Af1 + ((size_t)(w * 2 + i) * 64 + l) * 8);
    for (int ks = 0; ks < 8; ++ks) {
      f16x8 afn[2];
      if (ks < 7) {
#pragma unroll
        for (int i = 0; i < 2; ++i)
          afn[i] = *(const f16x8*)(Af1 + ((size_t)((ks + 1) * 16 + w * 2 + i) * 64 + l) * 8);
      }
      f16x8 bf[2];
#pragma unroll
      for (int j = 0; j < 2; ++j) {
        int n = j * 16 + lm;
        bf[j] = *(const f16x8*)(lds + n * 512 + (((ks * 4 + qq) ^ (n & 7)) * 16));
      }
#pragma unroll
      for (int i = 0; i < 2; ++i)
#pragma unroll
        for (int j = 0; j < 2; ++j)
          acc[i][j] = __builtin_amdgcn_mfma_f32_16x16x32_f16(af[i], bf[j], acc[i][j], 0, 0, 0);
#pragma unroll
      for (int i = 0; i < 2; ++i) af[i] = afn[i];
    }
  }

#pragma unroll
  for (int i = 0; i < 2; ++i) {
    const int mq = w * 32 + i * 16 + qq * 4;
    f32x4 s4 = *(const f32x4*)&bn1S[mq];
    f32x4 h4 = *(const f32x4*)&bn1H[mq];
#pragma unroll
    for (int r = 0; r < 4; ++r) {
      const int m = mq + r;
#pragma unroll
      for (int j = 0; j < 2; ++j) {
        int n = j * 16 + lm;
        out[(size_t)(b * CO + m) * Nn + n0 + n] = fmaxf(fmaf(acc[i][j][r], s4[r], h4[r]), 0.f);
      }
    }
  }
}

// ---------------------------------------------------------------- launch
extern "C" void kernel_launch(void* const* d_in, const int* in_sizes, int n_in,
                              void* d_out, int out_size, void* d_ws, size_t ws_size,
                              hipStream_t stream)
{
  const float* unknown = (const float*)d_in[0];
  const float* known   = (const float*)d_in[1];
  const float* uf      = (const float*)d_in[2];
  const float* kf      = (const float*)d_in[3];
  const float* W0  = (const float*)d_in[4];
  const float* b0  = (const float*)d_in[5];
  const float* g0  = (const float*)d_in[6];
  const float* be0 = (const float*)d_in[7];
  const float* rm0 = (const float*)d_in[8];
  const float* rv0 = (const float*)d_in[9];
  const float* W1  = (const float*)d_in[10];
  const float* b1  = (const float*)d_in[11];
  const float* g1  = (const float*)d_in[12];
  const float* be1 = (const float*)d_in[13];
  const float* rm1 = (const float*)d_in[14];
  const float* rv1 = (const float*)d_in[15];

  char* ws = (char*)d_ws;
  f16* kfT = (f16*)(ws + 0);          // B*M*C2 f16 = 4 MB
  f16* Af0 = (f16*)(ws + 4194304);    // 256*384 f16 (fragment-order)
  f16* Af1 = (f16*)(ws + 4390912);    // 256*256 f16 (fragment-order)
  float* out = (float*)d_out;         // (B,256,N) f32

  prep_kernel <<<dim3(32, 4, 5), 256, 0, stream>>>(kf, kfT, W0, W1, Af0, Af1);
  fused_kernel<<<dim3(Bb * (Nn / 32)), 512, 0, stream>>>(
      unknown, known, Af0, Af1, kfT, uf,
      b0, g0, be0, rm0, rv0, b1, g1, be1, rm1, rv1, out);
}